// Round 13
// baseline (639.768 us; speedup 1.0000x reference)
//
#include <hip/hip_runtime.h>
#include <cstddef>
#include <cstdint>

// ---------------- types / helpers ----------------
typedef short s16x8 __attribute__((ext_vector_type(8)));
typedef unsigned short u16x4 __attribute__((ext_vector_type(4)));
typedef unsigned short u16x8 __attribute__((ext_vector_type(8)));
typedef float f32x4 __attribute__((ext_vector_type(4)));

__device__ __forceinline__ unsigned short f2bf(float f) {
  unsigned int u = __float_as_uint(f);
  u = (u + 0x7fffu + ((u >> 16) & 1u)) >> 16;
  return (unsigned short)u;
}
__device__ __forceinline__ float bf2f(unsigned short u) {
  return __uint_as_float(((unsigned int)u) << 16);
}

__device__ __forceinline__ void gl2lds16(const unsigned short* g, unsigned short* l) {
  __builtin_amdgcn_global_load_lds(
      (const __attribute__((address_space(1))) unsigned int*)g,
      (__attribute__((address_space(3))) unsigned int*)l, 16, 0, 0);
}
__device__ __forceinline__ void gl2lds16f(const float* g, float* l) {
  __builtin_amdgcn_global_load_lds(
      (const __attribute__((address_space(1))) unsigned int*)g,
      (__attribute__((address_space(3))) unsigned int*)l, 16, 0, 0);
}

static inline size_t alignup(size_t x) { return (x + 255) & ~(size_t)255; }

// ---------------- graph preprocessing ----------------
__global__ void count_kernel(const int* __restrict__ dst, int* __restrict__ counts, int E) {
  int e = blockIdx.x * blockDim.x + threadIdx.x;
  if (e < E) atomicAdd(&counts[dst[e]], 1);
}

__global__ void block_sum_kernel(const int* __restrict__ counts, int* __restrict__ bsum, int n) {
  __shared__ int red[256];
  int i = blockIdx.x * 256 + threadIdx.x;
  red[threadIdx.x] = (i < n) ? counts[i] : 0;
  __syncthreads();
  #pragma unroll
  for (int o = 128; o > 0; o >>= 1) {
    if (threadIdx.x < o) red[threadIdx.x] += red[threadIdx.x + o];
    __syncthreads();
  }
  if (threadIdx.x == 0) bsum[blockIdx.x] = red[0];
}

__global__ void scan_bsum_kernel(int* __restrict__ bsum, int nb) {
  __shared__ int s[256];
  int t = threadIdx.x;
  s[t] = (t < nb) ? bsum[t] : 0;
  __syncthreads();
  #pragma unroll
  for (int o = 1; o < 256; o <<= 1) {
    int v = (t >= o) ? s[t - o] : 0;
    __syncthreads();
    s[t] += v;
    __syncthreads();
  }
  if (t < nb) bsum[t] = (t == 0) ? 0 : s[t - 1];  // exclusive
}

// scan_apply + fused invsqrt (counts already in registers)
__global__ void scan_apply_kernel(const int* __restrict__ counts, const int* __restrict__ bpre,
                                  int* __restrict__ offsets, float* __restrict__ inv_s, int n) {
  __shared__ int s[256];
  int t = threadIdx.x;
  int i = blockIdx.x * 256 + t;
  int c = (i < n) ? counts[i] : 0;
  s[t] = c;
  __syncthreads();
  #pragma unroll
  for (int o = 1; o < 256; o <<= 1) {
    int v = (t >= o) ? s[t - o] : 0;
    __syncthreads();
    s[t] += v;
    __syncthreads();
  }
  if (i < n) {
    offsets[i + 1] = s[t] + bpre[blockIdx.x];
    inv_s[i] = rsqrtf((float)(c + 1));  // +1 self loop
  }
  if (i == 0) offsets[0] = 0;
}

__global__ void fill_kernel(const int* __restrict__ src, const int* __restrict__ dst,
                            const int* __restrict__ offsets, int* __restrict__ cursor,
                            int* __restrict__ csr_src, int E) {
  int e = blockIdx.x * blockDim.x + threadIdx.x;
  if (e >= E) return;
  int d = dst[e];
  int pos = atomicAdd(&cursor[d], 1);
  csr_src[offsets[d] + pos] = src[e];
}

// ---------------- both weight transposes in one launch ----------------
// W[K][N] f32 -> Wt[N][K] bf16.  blocks 0..767: W1 (48x16), 768..831: W2 (16x4).
__global__ void transpose_both_kernel(const float* __restrict__ W1, unsigned short* __restrict__ W1t,
                                      const float* __restrict__ W2, unsigned short* __restrict__ W2t) {
  __shared__ float tile[32][33];
  int b = blockIdx.x;
  const float* W;
  unsigned short* Wt;
  int K, N, kx, ny;
  if (b < 768) { W = W1; Wt = W1t; K = 1536; N = 512; kx = b % 48; ny = b / 48; }
  else { b -= 768; W = W2; Wt = W2t; K = 512; N = 128; kx = b % 16; ny = b / 16; }
  int k0 = kx * 32, n0 = ny * 32;
  int tx = threadIdx.x & 31, ty = threadIdx.x >> 5;
  #pragma unroll
  for (int i = 0; i < 32; i += 8)
    tile[ty + i][tx] = W[(size_t)(k0 + ty + i) * N + n0 + tx];
  __syncthreads();
  #pragma unroll
  for (int i = 0; i < 32; i += 8)
    Wt[(size_t)(n0 + ty + i) * K + k0 + tx] = f2bf(tile[tx][ty + i]);
}

// ---------------- GEMM1: f32 A[M][1536] x Bt[512][1536] bf16 -> C[M][512] bf16 --------------
// R10 form — FROZEN. 2 buffers, 1 __syncthreads/tile, all global_load_lds, cvt_pk in
// fragment path, 8 waves (2x4) of 64x64, 64KB LDS (2 blk/CU, the measured optimum).
// A: 128B rows, 8 slots, slot^(row&7) (bank-free). B: 64B rows, slot^((row>>1)&3) (bank-free).
__global__ __launch_bounds__(512) void gemm1_kernel(
    const float* __restrict__ A, const unsigned short* __restrict__ B,
    unsigned short* __restrict__ C, int M) {
  __shared__ __align__(16) float As[2][128 * 32];
  __shared__ __align__(16) unsigned short Bs[2][256 * 32];
  const int K = 1536;
  const int NT = 48;  // K / 32
  int tid = threadIdx.x, lane = tid & 63, w = tid >> 6;

  // bijective XCD swizzle (m204)
  int nwg = gridDim.x * gridDim.y;  // 782
  int orig = blockIdx.y * gridDim.x + blockIdx.x;
  int q = nwg >> 3, r = nwg & 7;
  int xcd = orig & 7, loc = orig >> 3;
  int wg = (xcd < r) ? xcd * (q + 1) + loc : r * (q + 1) + (xcd - r) * q + loc;
  int bx = wg & 1, by = wg >> 1;  // gridDim.x == 2

  int m0 = by * 128, n0 = bx * 256;
  int wm = (w >> 2) * 64, wn = (w & 3) * 64;

  f32x4 acc[4][4];
  #pragma unroll
  for (int i = 0; i < 4; i++)
    #pragma unroll
    for (int j = 0; j < 4; j++) acc[i][j] = (f32x4){0.f, 0.f, 0.f, 0.f};

  // A staging (f32): 128x32 = 16KB = 2 passes x (512 thr x 16B). row=idx>>3, slot=idx&7.
  int row0 = tid >> 3, slot0 = tid & 7;
  int row1 = 64 + row0;
  const float* agp0 = &A[(size_t)min(m0 + row0, M - 1) * K + ((slot0 ^ (row0 & 7)) << 2)];
  const float* agp1 = &A[(size_t)min(m0 + row1, M - 1) * K + ((slot0 ^ (row1 & 7)) << 2)];
  int adst0 = tid * 4, adst1 = (512 + tid) * 4;  // f32 elems, linear
  // B staging (bf16): 256x32 = 16KB = 2 passes. row = tid>>2, 4 slots of 8 bf16.
  int brow = tid >> 2, bslot = tid & 3;
  int bsrc = (bslot ^ ((brow >> 1) & 3)) << 3;
  const unsigned short* bgp0 = &B[(size_t)(n0 + brow) * K + bsrc];
  const unsigned short* bgp1 = &B[(size_t)(n0 + 128 + brow) * K + bsrc];
  int bdst0 = tid * 8, bdst1 = (512 + tid) * 8;

  // prologue: stage tile 0 into buf 0
  gl2lds16f(agp0, &As[0][adst0]);
  gl2lds16f(agp1, &As[0][adst1]);
  gl2lds16(bgp0, &Bs[0][bdst0]);
  gl2lds16(bgp1, &Bs[0][bdst1]);
  __syncthreads();

  int cur = 0;
  for (int t = 0; t < NT; t++) {
    if (t + 1 < NT) {
      int kb = (t + 1) * 32;
      gl2lds16f(agp0 + kb, &As[cur ^ 1][adst0]);
      gl2lds16f(agp1 + kb, &As[cur ^ 1][adst1]);
      gl2lds16(bgp0 + kb, &Bs[cur ^ 1][bdst0]);
      gl2lds16(bgp1 + kb, &Bs[cur ^ 1][bdst1]);
    }
    // fragments from buf[cur]; A converted f32->bf16 here
    int jc = lane >> 4;  // 0..3
    s16x8 af[4], bfr[4];
    #pragma unroll
    for (int i = 0; i < 4; i++) {
      int rr = wm + i * 16 + (lane & 15);
      f32x4 v0 = *reinterpret_cast<const f32x4*>(&As[cur][rr * 32 + (((2 * jc) ^ (rr & 7)) << 2)]);
      f32x4 v1 = *reinterpret_cast<const f32x4*>(&As[cur][rr * 32 + (((2 * jc + 1) ^ (rr & 7)) << 2)]);
      unsigned int c0, c1, c2, c3;
      asm("v_cvt_pk_bf16_f32 %0, %1, %2" : "=v"(c0) : "v"(v0[0]), "v"(v0[1]));
      asm("v_cvt_pk_bf16_f32 %0, %1, %2" : "=v"(c1) : "v"(v0[2]), "v"(v0[3]));
      asm("v_cvt_pk_bf16_f32 %0, %1, %2" : "=v"(c2) : "v"(v1[0]), "v"(v1[1]));
      asm("v_cvt_pk_bf16_f32 %0, %1, %2" : "=v"(c3) : "v"(v1[2]), "v"(v1[3]));
      uint4 pk;
      pk.x = c0; pk.y = c1; pk.z = c2; pk.w = c3;
      af[i] = __builtin_bit_cast(s16x8, pk);
      int rn = wn + i * 16 + (lane & 15);
      bfr[i] = *reinterpret_cast<const s16x8*>(
          &Bs[cur][rn * 32 + ((jc ^ ((rn >> 1) & 3)) << 3)]);
    }
    #pragma unroll
    for (int i = 0; i < 4; i++)
      #pragma unroll
      for (int j = 0; j < 4; j++)
        acc[i][j] = __builtin_amdgcn_mfma_f32_16x16x32_bf16(af[i], bfr[j], acc[i][j], 0, 0, 0);
    __syncthreads();  // drains next-tile DMA (flew under MFMA) + frees buf[cur]
    cur ^= 1;
  }

  #pragma unroll
  for (int i = 0; i < 4; i++) {
    #pragma unroll
    for (int j = 0; j < 4; j++) {
      int col = n0 + wn + j * 16 + (lane & 15);
      #pragma unroll
      for (int r2 = 0; r2 < 4; r2++) {
        int row = m0 + wm + i * 16 + (lane >> 4) * 4 + r2;
        if (row < M) C[(size_t)row * 512 + col] = f2bf(acc[i][j][r2]);
      }
    }
  }
}

// ---------------- GEMM2: bf16 A (BN1+ReLU fused) x W2t bf16 -> C bf16 ----------------
// BM=64 (782 blocks). BN finalize fused: each block derives scale/shift from accum into LDS.
#define LDT 72
__global__ __launch_bounds__(256) void gemm2_kernel(
    const unsigned short* __restrict__ A, const unsigned short* __restrict__ Bt,
    const float* __restrict__ accum, const float* __restrict__ gamma,
    const float* __restrict__ beta, unsigned short* __restrict__ C, int M, float invN) {
  const int N = 128, K = 512;
  __shared__ unsigned short As[64 * LDT];
  __shared__ unsigned short Bs[128 * LDT];
  __shared__ float scs[512], shs[512];
  int tid = threadIdx.x;
  int m0 = blockIdx.y * 64;
  int w = tid >> 6, lane = tid & 63;
  int wm = (w >> 1) * 32, wn = (w & 1) * 64;

  // fused BN1 finalize (per-block, redundant but trivial)
  for (int c = tid; c < 512; c += 256) {
    float mean = accum[c] * invN;
    float var = accum[512 + c] * invN - mean * mean;
    float s = gamma[c] * rsqrtf(var + 1e-5f);
    scs[c] = s;
    shs[c] = beta[c] - mean * s;
  }
  __syncthreads();

  f32x4 acc[2][4];
  #pragma unroll
  for (int i = 0; i < 2; i++)
    #pragma unroll
    for (int j = 0; j < 4; j++) acc[i][j] = (f32x4){0.f, 0.f, 0.f, 0.f};

  for (int k0 = 0; k0 < K; k0 += 64) {
    // stage A: BN+ReLU on the fly (64 rows x 8 segs = 512 slots, 2/thread)
    #pragma unroll
    for (int r = 0; r < 2; r++) {
      int idx = r * 256 + tid;        // 0..511
      int row = idx >> 3;             // 0..63
      int seg = (idx & 7) * 8;        // 0..56
      int gr = m0 + row;
      u16x8 v = (u16x8){0, 0, 0, 0, 0, 0, 0, 0};
      if (gr < M) v = *reinterpret_cast<const u16x8*>(&A[(size_t)gr * K + k0 + seg]);
      int c = k0 + seg;
      u16x8 p;
      #pragma unroll
      for (int j = 0; j < 8; j++) {
        float f = fmaxf(bf2f(v[j]) * scs[c + j] + shs[c + j], 0.f);
        p[j] = f2bf(f);
      }
      *reinterpret_cast<u16x8*>(&As[row * LDT + seg]) = p;
    }
    // stage B (128 rows x 8 segs = 1024 slots, 4/thread)
    #pragma unroll
    for (int r = 0; r < 4; r++) {
      int idx = r * 256 + tid;
      int n = idx >> 3;
      int seg = (idx & 7) * 8;
      u16x8 v = *reinterpret_cast<const u16x8*>(&Bt[(size_t)n * K + k0 + seg]);
      *reinterpret_cast<u16x8*>(&Bs[n * LDT + seg]) = v;
    }
    __syncthreads();
    #pragma unroll
    for (int ks = 0; ks < 2; ks++) {
      s16x8 af[2], bfr[4];
      #pragma unroll
      for (int i = 0; i < 2; i++)
        af[i] = *reinterpret_cast<const s16x8*>(
            &As[(wm + i * 16 + (lane & 15)) * LDT + ks * 32 + (lane >> 4) * 8]);
      #pragma unroll
      for (int j = 0; j < 4; j++)
        bfr[j] = *reinterpret_cast<const s16x8*>(
            &Bs[(wn + j * 16 + (lane & 15)) * LDT + ks * 32 + (lane >> 4) * 8]);
      #pragma unroll
      for (int i = 0; i < 2; i++)
        #pragma unroll
        for (int j = 0; j < 4; j++)
          acc[i][j] = __builtin_amdgcn_mfma_f32_16x16x32_bf16(af[i], bfr[j], acc[i][j], 0, 0, 0);
    }
    __syncthreads();
  }
  #pragma unroll
  for (int i = 0; i < 2; i++) {
    #pragma unroll
    for (int j = 0; j < 4; j++) {
      int col = wn + j * 16 + (lane & 15);
      #pragma unroll
      for (int r = 0; r < 4; r++) {
        int row = m0 + wm + i * 16 + (lane >> 4) * 4 + r;
        if (row < M) C[(size_t)row * N + col] = f2bf(acc[i][j][r]);
      }
    }
  }
}

// ---------------- aggregation + fused BN stats (bf16 in / bf16 out, fp32 accum) -------------
// 4 nodes/wave (3125 blocks, ~48 waves/CU oversubscribed) + 8-deep edge unroll:
// 8 independent 1KB-row gathers in flight per lane. Fused per-channel sum/sumsq stats
// (on the STORED bf16 value, matching the previous bn_stats pass semantics).
__global__ void agg512_kernel(const unsigned short* __restrict__ h, const int* __restrict__ offsets,
                              const int* __restrict__ csr, const float* __restrict__ inv_s,
                              unsigned short* __restrict__ out, float* __restrict__ accum, int n) {
  __shared__ float rs[512], rq[512];
  int wv = threadIdx.x >> 6, lane = threadIdx.x & 63;
  for (int c = threadIdx.x; c < 512; c += 256) { rs[c] = 0.f; rq[c] = 0.f; }
  __syncthreads();
  const u16x8* h8 = reinterpret_cast<const u16x8*>(h);  // 64 segs/row
  float s[8], qsum[8];
  #pragma unroll
  for (int j = 0; j < 8; j++) { s[j] = 0.f; qsum[j] = 0.f; }
  for (int i = 0; i < 4; i++) {
    int node = blockIdx.x * 16 + wv * 4 + i;
    if (node >= n) break;
    float di = inv_s[node];
    size_t rb = (size_t)node * 64;
    float acc[8];
    u16x8 v0 = h8[rb + lane];
    float dd = di * di;
    #pragma unroll
    for (int j = 0; j < 8; j++) acc[j] = bf2f(v0[j]) * dd;
    int e = offsets[node], e1 = offsets[node + 1];
    for (; e + 7 < e1; e += 8) {
      int si[8];
      float wi[8];
      u16x8 vi[8];
      #pragma unroll
      for (int k = 0; k < 8; k++) si[k] = csr[e + k];
      #pragma unroll
      for (int k = 0; k < 8; k++) wi[k] = inv_s[si[k]] * di;
      #pragma unroll
      for (int k = 0; k < 8; k++) vi[k] = h8[(size_t)si[k] * 64 + lane];
      #pragma unroll
      for (int j = 0; j < 8; j++) {
        float a = acc[j];
        #pragma unroll
        for (int k = 0; k < 8; k++) a += bf2f(vi[k][j]) * wi[k];
        acc[j] = a;
      }
    }
    for (; e < e1; e++) {
      int sA = csr[e];
      float wA = inv_s[sA] * di;
      u16x8 vA = h8[(size_t)sA * 64 + lane];
      #pragma unroll
      for (int j = 0; j < 8; j++) acc[j] += bf2f(vA[j]) * wA;
    }
    u16x8 o;
    #pragma unroll
    for (int j = 0; j < 8; j++) {
      unsigned short b = f2bf(acc[j]);
      o[j] = b;
      float gv = bf2f(b);  // stats on the STORED bf16 value
      s[j] += gv;
      qsum[j] += gv * gv;
    }
    reinterpret_cast<u16x8*>(out)[rb + lane] = o;
  }
  #pragma unroll
  for (int j = 0; j < 8; j++) {
    atomicAdd(&rs[lane * 8 + j], s[j]);
    atomicAdd(&rq[lane * 8 + j], qsum[j]);
  }
  __syncthreads();
  for (int c = threadIdx.x; c < 512; c += 256) {
    atomicAdd(&accum[c], rs[c]);
    atomicAdd(&accum[512 + c], rq[c]);
  }
}

__global__ void agg128_kernel(const unsigned short* __restrict__ h, const int* __restrict__ offsets,
                              const int* __restrict__ csr, const float* __restrict__ inv_s,
                              unsigned short* __restrict__ out, float* __restrict__ accum, int n) {
  __shared__ float rs[128], rq[128];
  int wv = threadIdx.x >> 6, lane = threadIdx.x & 63;
  if (threadIdx.x < 128) { rs[threadIdx.x] = 0.f; rq[threadIdx.x] = 0.f; }
  __syncthreads();
  const unsigned int* h2 = reinterpret_cast<const unsigned int*>(h);  // 64 uints/row
  float s0 = 0.f, q0 = 0.f, s1 = 0.f, q1 = 0.f;
  for (int i = 0; i < 4; i++) {
    int node = blockIdx.x * 16 + wv * 4 + i;
    if (node >= n) break;
    float di = inv_s[node];
    size_t rb = (size_t)node * 64;
    unsigned int u0 = h2[rb + lane];
    float dd = di * di;
    float alo = __uint_as_float(u0 << 16) * dd;
    float ahi = __uint_as_float(u0 & 0xffff0000u) * dd;
    int e = offsets[node], e1 = offsets[node + 1];
    for (; e + 7 < e1; e += 8) {
      int si[8];
      float wi[8];
      unsigned int ui[8];
      #pragma unroll
      for (int k = 0; k < 8; k++) si[k] = csr[e + k];
      #pragma unroll
      for (int k = 0; k < 8; k++) wi[k] = inv_s[si[k]] * di;
      #pragma unroll
      for (int k = 0; k < 8; k++) ui[k] = h2[(size_t)si[k] * 64 + lane];
      #pragma unroll
      for (int k = 0; k < 8; k++) {
        alo += __uint_as_float(ui[k] << 16) * wi[k];
        ahi += __uint_as_float(ui[k] & 0xffff0000u) * wi[k];
      }
    }
    for (; e < e1; e++) {
      int sA = csr[e];
      float wA = inv_s[sA] * di;
      unsigned int uA = h2[(size_t)sA * 64 + lane];
      alo += __uint_as_float(uA << 16) * wA;
      ahi += __uint_as_float(uA & 0xffff0000u) * wA;
    }
    unsigned short blo = f2bf(alo), bhi = f2bf(ahi);
    unsigned int uo = ((unsigned int)bhi << 16) | (unsigned int)blo;
    reinterpret_cast<unsigned int*>(out)[rb + lane] = uo;
    float glo = bf2f(blo), ghi = bf2f(bhi);
    s0 += glo; q0 += glo * glo; s1 += ghi; q1 += ghi * ghi;
  }
  atomicAdd(&rs[2 * lane], s0);
  atomicAdd(&rq[2 * lane], q0);
  atomicAdd(&rs[2 * lane + 1], s1);
  atomicAdd(&rq[2 * lane + 1], q1);
  __syncthreads();
  if (threadIdx.x < 128) {
    atomicAdd(&accum[threadIdx.x], rs[threadIdx.x]);
    atomicAdd(&accum[128 + threadIdx.x], rq[threadIdx.x]);
  }
}

// ---------------- layer 3: tiny GEMM K=128, N=5 (fp32), BN2 finalize+ReLU fused ----------------
__global__ void gemm3_kernel(const unsigned short* __restrict__ A, const float* __restrict__ W,
                             const float* __restrict__ accum, const float* __restrict__ gamma,
                             const float* __restrict__ beta, float* __restrict__ C, int M,
                             float invN) {
  __shared__ float Ws[128 * 5];
  __shared__ float scs[128], shs[128];
  int tid = threadIdx.x;
  for (int i = tid; i < 128 * 5; i += blockDim.x) Ws[i] = W[i];
  if (tid < 128) {
    float mean = accum[tid] * invN;
    float var = accum[128 + tid] * invN - mean * mean;
    float s = gamma[tid] * rsqrtf(var + 1e-5f);
    scs[tid] = s;
    shs[tid] = beta[tid] - mean * s;
  }
  __syncthreads();
  int row = blockIdx.x * blockDim.x + tid;
  if (row >= M) return;
  float acc[5] = {0.f, 0.f, 0.f, 0.f, 0.f};
  const u16x8* a8 = reinterpret_cast<const u16x8*>(A + (size_t)row * 128);
  for (int k8 = 0; k8 < 16; k8++) {
    u16x8 v = a8[k8];
    int k = k8 * 8;
    #pragma unroll
    for (int j = 0; j < 8; j++) {
      float f = fmaxf(bf2f(v[j]) * scs[k + j] + shs[k + j], 0.f);
      #pragma unroll
      for (int c = 0; c < 5; c++) acc[c] += f * Ws[(k + j) * 5 + c];
    }
  }
  #pragma unroll
  for (int j = 0; j < 5; j++) C[(size_t)row * 5 + j] = acc[j];
}

// ---------------- final aggregation + b3 + log_softmax ----------------
__global__ void agg3_lsm_kernel(const float* __restrict__ h, const int* __restrict__ offsets,
                                const int* __restrict__ csr, const float* __restrict__ inv_s,
                                const float* __restrict__ b3, float* __restrict__ out, int n) {
  int node = blockIdx.x * blockDim.x + threadIdx.x;
  if (node >= n) return;
  float di = inv_s[node];
  float acc[5];
  #pragma unroll
  for (int j = 0; j < 5; j++) acc[j] = h[(size_t)node * 5 + j] * di * di;
  int s0 = offsets[node], s1 = offsets[node + 1];
  for (int e = s0; e < s1; e++) {
    int s = csr[e];
    float wgt = inv_s[s] * di;
    #pragma unroll
    for (int j = 0; j < 5; j++) acc[j] += h[(size_t)s * 5 + j] * wgt;
  }
  #pragma unroll
  for (int j = 0; j < 5; j++) acc[j] += b3[j];
  float m = acc[0];
  #pragma unroll
  for (int j = 1; j < 5; j++) m = fmaxf(m, acc[j]);
  float sum = 0.f;
  #pragma unroll
  for (int j = 0; j < 5; j++) sum += expf(acc[j] - m);
  float lse = logf(sum);
  #pragma unroll
  for (int j = 0; j < 5; j++) out[(size_t)node * 5 + j] = acc[j] - m - lse;
}

// ---------------- launcher ----------------
extern "C" void kernel_launch(void* const* d_in, const int* in_sizes, int n_in,
                              void* d_out, int out_size, void* d_ws, size_t ws_size,
                              hipStream_t stream) {
  const float* x      = (const float*)d_in[0];
  const int*   ei     = (const int*)d_in[1];
  const float* W1     = (const float*)d_in[2];
  const float* b3     = (const float*)d_in[7];
  const float* W2     = (const float*)d_in[4];
  const float* W3     = (const float*)d_in[6];
  const float* gamma1 = (const float*)d_in[8];
  const float* beta1  = (const float*)d_in[9];
  const float* gamma2 = (const float*)d_in[10];
  const float* beta2  = (const float*)d_in[11];

  const int N = in_sizes[0] / 1536;
  const int E = in_sizes[1] / 2;
  const int* src = ei;
  const int* dst = ei + E;

  const int mblocks = (N + 127) / 128;      // 391
  const int Mpad = mblocks * 128;           // 50048
  const int nb = (N + 255) / 256;

  char* ws = (char*)d_ws;
  size_t szRA = alignup((size_t)N * 512 * sizeof(float));
  size_t szXB = alignup((size_t)Mpad * 1536 * sizeof(unsigned short));
  char* RAb = ws;                            // region A (bf16 H1 / bf16 H2 / f32 H3)
  char* RBb = ws + szRA;                     // region B (G1/G2)
  char* sp = ws + szRA + szXB;
  // zero-initialized group (one memset): counts, cursor, accumA, accumB
  char* zbase = sp;
  int* counts    = (int*)sp;          sp += alignup((size_t)N * 4);
  int* cursor    = (int*)sp;          sp += alignup((size_t)N * 4);
  float* accumA  = (float*)sp;        sp += alignup(1024 * 4);
  float* accumB  = (float*)sp;        sp += alignup(256 * 4);
  size_t zspan = (size_t)(sp - zbase);
  int* offsets  = (int*)sp;           sp += alignup((size_t)(N + 1) * 4);
  int* csr_src  = (int*)sp;           sp += alignup((size_t)E * 4);
  float* inv_s  = (float*)sp;         sp += alignup((size_t)N * 4);
  unsigned short* W1t = (unsigned short*)sp; sp += alignup((size_t)512 * 1536 * 2);
  unsigned short* W2t = (unsigned short*)sp; sp += alignup((size_t)128 * 512 * 2);
  int* bsum     = (int*)sp;           sp += alignup(256 * 4);

  unsigned short* H1  = (unsigned short*)RAb;  // N x 512 bf16
  unsigned short* G1  = (unsigned short*)RBb;  // N x 512 bf16 (post-agg)
  unsigned short* H2  = (unsigned short*)RAb;  // N x 128 bf16
  unsigned short* G2  = (unsigned short*)RBb;  // N x 128 bf16
  float*          H3  = (float*)RAb;           // N x 5 f32

  // ---- single memset for all zero-init scratch ----
  hipMemsetAsync(zbase, 0, zspan, stream);

  // ---- graph preprocessing ----
  count_kernel<<<(E + 255) / 256, 256, 0, stream>>>(dst, counts, E);
  block_sum_kernel<<<nb, 256, 0, stream>>>(counts, bsum, N);
  scan_bsum_kernel<<<1, 256, 0, stream>>>(bsum, nb);
  scan_apply_kernel<<<nb, 256, 0, stream>>>(counts, bsum, offsets, inv_s, N);
  fill_kernel<<<(E + 255) / 256, 256, 0, stream>>>(src, dst, offsets, cursor, csr_src, E);

  // ---- weights (both transposes, one launch) ----
  transpose_both_kernel<<<832, 256, 0, stream>>>(W1, W1t, W2, W2t);

  int aggblocks16 = (N + 15) / 16;
  float invN = 1.0f / N;

  // ---- layer 1 (f32 x staged directly; cvt fused into fragment path) ----
  gemm1_kernel<<<dim3(2, mblocks), 512, 0, stream>>>(x, W1t, H1, N);
  agg512_kernel<<<aggblocks16, 256, 0, stream>>>(H1, offsets, csr_src, inv_s, G1, accumA, N);

  // ---- layer 2 (BN1 finalize + ReLU fused into A staging; BM=64 balanced grid) ----
  gemm2_kernel<<<dim3(1, (N + 63) / 64), 256, 0, stream>>>(G1, W2t, accumA, gamma1, beta1, H2, N,
                                                           invN);
  agg128_kernel<<<aggblocks16, 256, 0, stream>>>(H2, offsets, csr_src, inv_s, G2, accumB, N);

  // ---- layer 3 (BN2 finalize + ReLU fused) ----
  gemm3_kernel<<<(N + 255) / 256, 256, 0, stream>>>(G2, W3, accumB, gamma2, beta2, H3, N, invN);
  agg3_lsm_kernel<<<(N + 255) / 256, 256, 0, stream>>>(H3, offsets, csr_src, inv_s, b3,
                                                       (float*)d_out, N);
}

// Round 14
// 558.797 us; speedup vs baseline: 1.1449x; 1.1449x over previous
//
#include <hip/hip_runtime.h>
#include <cstddef>
#include <cstdint>

// ---------------- types / helpers ----------------
typedef short s16x8 __attribute__((ext_vector_type(8)));
typedef unsigned short u16x4 __attribute__((ext_vector_type(4)));
typedef unsigned short u16x8 __attribute__((ext_vector_type(8)));
typedef float f32x4 __attribute__((ext_vector_type(4)));

__device__ __forceinline__ unsigned short f2bf(float f) {
  unsigned int u = __float_as_uint(f);
  u = (u + 0x7fffu + ((u >> 16) & 1u)) >> 16;
  return (unsigned short)u;
}
__device__ __forceinline__ float bf2f(unsigned short u) {
  return __uint_as_float(((unsigned int)u) << 16);
}

__device__ __forceinline__ void gl2lds16(const unsigned short* g, unsigned short* l) {
  __builtin_amdgcn_global_load_lds(
      (const __attribute__((address_space(1))) unsigned int*)g,
      (__attribute__((address_space(3))) unsigned int*)l, 16, 0, 0);
}
__device__ __forceinline__ void gl2lds16f(const float* g, float* l) {
  __builtin_amdgcn_global_load_lds(
      (const __attribute__((address_space(1))) unsigned int*)g,
      (__attribute__((address_space(3))) unsigned int*)l, 16, 0, 0);
}

static inline size_t alignup(size_t x) { return (x + 255) & ~(size_t)255; }

// ---------------- graph preprocessing ----------------
__global__ void count_kernel(const int* __restrict__ dst, int* __restrict__ counts, int E) {
  int e = blockIdx.x * blockDim.x + threadIdx.x;
  if (e < E) atomicAdd(&counts[dst[e]], 1);
}

__global__ void block_sum_kernel(const int* __restrict__ counts, int* __restrict__ bsum, int n) {
  __shared__ int red[256];
  int i = blockIdx.x * 256 + threadIdx.x;
  red[threadIdx.x] = (i < n) ? counts[i] : 0;
  __syncthreads();
  #pragma unroll
  for (int o = 128; o > 0; o >>= 1) {
    if (threadIdx.x < o) red[threadIdx.x] += red[threadIdx.x + o];
    __syncthreads();
  }
  if (threadIdx.x == 0) bsum[blockIdx.x] = red[0];
}

__global__ void scan_bsum_kernel(int* __restrict__ bsum, int nb) {
  __shared__ int s[256];
  int t = threadIdx.x;
  s[t] = (t < nb) ? bsum[t] : 0;
  __syncthreads();
  #pragma unroll
  for (int o = 1; o < 256; o <<= 1) {
    int v = (t >= o) ? s[t - o] : 0;
    __syncthreads();
    s[t] += v;
    __syncthreads();
  }
  if (t < nb) bsum[t] = (t == 0) ? 0 : s[t - 1];  // exclusive
}

// scan_apply + fused invsqrt (counts already in registers)
__global__ void scan_apply_kernel(const int* __restrict__ counts, const int* __restrict__ bpre,
                                  int* __restrict__ offsets, float* __restrict__ inv_s, int n) {
  __shared__ int s[256];
  int t = threadIdx.x;
  int i = blockIdx.x * 256 + t;
  int c = (i < n) ? counts[i] : 0;
  s[t] = c;
  __syncthreads();
  #pragma unroll
  for (int o = 1; o < 256; o <<= 1) {
    int v = (t >= o) ? s[t - o] : 0;
    __syncthreads();
    s[t] += v;
    __syncthreads();
  }
  if (i < n) {
    offsets[i + 1] = s[t] + bpre[blockIdx.x];
    inv_s[i] = rsqrtf((float)(c + 1));  // +1 self loop
  }
  if (i == 0) offsets[0] = 0;
}

__global__ void fill_kernel(const int* __restrict__ src, const int* __restrict__ dst,
                            const int* __restrict__ offsets, int* __restrict__ cursor,
                            int* __restrict__ csr_src, int E) {
  int e = blockIdx.x * blockDim.x + threadIdx.x;
  if (e >= E) return;
  int d = dst[e];
  int pos = atomicAdd(&cursor[d], 1);
  csr_src[offsets[d] + pos] = src[e];
}

// ---------------- both weight transposes in one launch ----------------
// W[K][N] f32 -> Wt[N][K] bf16.  blocks 0..767: W1 (48x16), 768..831: W2 (16x4).
__global__ void transpose_both_kernel(const float* __restrict__ W1, unsigned short* __restrict__ W1t,
                                      const float* __restrict__ W2, unsigned short* __restrict__ W2t) {
  __shared__ float tile[32][33];
  int b = blockIdx.x;
  const float* W;
  unsigned short* Wt;
  int K, N, kx, ny;
  if (b < 768) { W = W1; Wt = W1t; K = 1536; N = 512; kx = b % 48; ny = b / 48; }
  else { b -= 768; W = W2; Wt = W2t; K = 512; N = 128; kx = b % 16; ny = b / 16; }
  int k0 = kx * 32, n0 = ny * 32;
  int tx = threadIdx.x & 31, ty = threadIdx.x >> 5;
  #pragma unroll
  for (int i = 0; i < 32; i += 8)
    tile[ty + i][tx] = W[(size_t)(k0 + ty + i) * N + n0 + tx];
  __syncthreads();
  #pragma unroll
  for (int i = 0; i < 32; i += 8)
    Wt[(size_t)(n0 + ty + i) * K + k0 + tx] = f2bf(tile[tx][ty + i]);
}

// ---------------- GEMM1: f32 A[M][1536] x Bt[512][1536] bf16 -> C[M][512] bf16 --------------
// R10 form — FROZEN. 2 buffers, 1 __syncthreads/tile, all global_load_lds, cvt_pk in
// fragment path, 8 waves (2x4) of 64x64, 64KB LDS (2 blk/CU, the measured optimum).
// A: 128B rows, 8 slots, slot^(row&7) (bank-free). B: 64B rows, slot^((row>>1)&3) (bank-free).
__global__ __launch_bounds__(512) void gemm1_kernel(
    const float* __restrict__ A, const unsigned short* __restrict__ B,
    unsigned short* __restrict__ C, int M) {
  __shared__ __align__(16) float As[2][128 * 32];
  __shared__ __align__(16) unsigned short Bs[2][256 * 32];
  const int K = 1536;
  const int NT = 48;  // K / 32
  int tid = threadIdx.x, lane = tid & 63, w = tid >> 6;

  // bijective XCD swizzle (m204)
  int nwg = gridDim.x * gridDim.y;  // 782
  int orig = blockIdx.y * gridDim.x + blockIdx.x;
  int q = nwg >> 3, r = nwg & 7;
  int xcd = orig & 7, loc = orig >> 3;
  int wg = (xcd < r) ? xcd * (q + 1) + loc : r * (q + 1) + (xcd - r) * q + loc;
  int bx = wg & 1, by = wg >> 1;  // gridDim.x == 2

  int m0 = by * 128, n0 = bx * 256;
  int wm = (w >> 2) * 64, wn = (w & 3) * 64;

  f32x4 acc[4][4];
  #pragma unroll
  for (int i = 0; i < 4; i++)
    #pragma unroll
    for (int j = 0; j < 4; j++) acc[i][j] = (f32x4){0.f, 0.f, 0.f, 0.f};

  // A staging (f32): 128x32 = 16KB = 2 passes x (512 thr x 16B). row=idx>>3, slot=idx&7.
  int row0 = tid >> 3, slot0 = tid & 7;
  int row1 = 64 + row0;
  const float* agp0 = &A[(size_t)min(m0 + row0, M - 1) * K + ((slot0 ^ (row0 & 7)) << 2)];
  const float* agp1 = &A[(size_t)min(m0 + row1, M - 1) * K + ((slot0 ^ (row1 & 7)) << 2)];
  int adst0 = tid * 4, adst1 = (512 + tid) * 4;  // f32 elems, linear
  // B staging (bf16): 256x32 = 16KB = 2 passes. row = tid>>2, 4 slots of 8 bf16.
  int brow = tid >> 2, bslot = tid & 3;
  int bsrc = (bslot ^ ((brow >> 1) & 3)) << 3;
  const unsigned short* bgp0 = &B[(size_t)(n0 + brow) * K + bsrc];
  const unsigned short* bgp1 = &B[(size_t)(n0 + 128 + brow) * K + bsrc];
  int bdst0 = tid * 8, bdst1 = (512 + tid) * 8;

  // prologue: stage tile 0 into buf 0
  gl2lds16f(agp0, &As[0][adst0]);
  gl2lds16f(agp1, &As[0][adst1]);
  gl2lds16(bgp0, &Bs[0][bdst0]);
  gl2lds16(bgp1, &Bs[0][bdst1]);
  __syncthreads();

  int cur = 0;
  for (int t = 0; t < NT; t++) {
    if (t + 1 < NT) {
      int kb = (t + 1) * 32;
      gl2lds16f(agp0 + kb, &As[cur ^ 1][adst0]);
      gl2lds16f(agp1 + kb, &As[cur ^ 1][adst1]);
      gl2lds16(bgp0 + kb, &Bs[cur ^ 1][bdst0]);
      gl2lds16(bgp1 + kb, &Bs[cur ^ 1][bdst1]);
    }
    // fragments from buf[cur]; A converted f32->bf16 here
    int jc = lane >> 4;  // 0..3
    s16x8 af[4], bfr[4];
    #pragma unroll
    for (int i = 0; i < 4; i++) {
      int rr = wm + i * 16 + (lane & 15);
      f32x4 v0 = *reinterpret_cast<const f32x4*>(&As[cur][rr * 32 + (((2 * jc) ^ (rr & 7)) << 2)]);
      f32x4 v1 = *reinterpret_cast<const f32x4*>(&As[cur][rr * 32 + (((2 * jc + 1) ^ (rr & 7)) << 2)]);
      unsigned int c0, c1, c2, c3;
      asm("v_cvt_pk_bf16_f32 %0, %1, %2" : "=v"(c0) : "v"(v0[0]), "v"(v0[1]));
      asm("v_cvt_pk_bf16_f32 %0, %1, %2" : "=v"(c1) : "v"(v0[2]), "v"(v0[3]));
      asm("v_cvt_pk_bf16_f32 %0, %1, %2" : "=v"(c2) : "v"(v1[0]), "v"(v1[1]));
      asm("v_cvt_pk_bf16_f32 %0, %1, %2" : "=v"(c3) : "v"(v1[2]), "v"(v1[3]));
      uint4 pk;
      pk.x = c0; pk.y = c1; pk.z = c2; pk.w = c3;
      af[i] = __builtin_bit_cast(s16x8, pk);
      int rn = wn + i * 16 + (lane & 15);
      bfr[i] = *reinterpret_cast<const s16x8*>(
          &Bs[cur][rn * 32 + ((jc ^ ((rn >> 1) & 3)) << 3)]);
    }
    #pragma unroll
    for (int i = 0; i < 4; i++)
      #pragma unroll
      for (int j = 0; j < 4; j++)
        acc[i][j] = __builtin_amdgcn_mfma_f32_16x16x32_bf16(af[i], bfr[j], acc[i][j], 0, 0, 0);
    __syncthreads();  // drains next-tile DMA (flew under MFMA) + frees buf[cur]
    cur ^= 1;
  }

  #pragma unroll
  for (int i = 0; i < 4; i++) {
    #pragma unroll
    for (int j = 0; j < 4; j++) {
      int col = n0 + wn + j * 16 + (lane & 15);
      #pragma unroll
      for (int r2 = 0; r2 < 4; r2++) {
        int row = m0 + wm + i * 16 + (lane >> 4) * 4 + r2;
        if (row < M) C[(size_t)row * 512 + col] = f2bf(acc[i][j][r2]);
      }
    }
  }
}

// ---------------- GEMM2: bf16 A (BN1+ReLU fused) x W2t bf16 -> C bf16 ----------------
// BM=64 (782 blocks). BN finalize fused: each block derives scale/shift from accum into LDS.
#define LDT 72
__global__ __launch_bounds__(256) void gemm2_kernel(
    const unsigned short* __restrict__ A, const unsigned short* __restrict__ Bt,
    const float* __restrict__ accum, const float* __restrict__ gamma,
    const float* __restrict__ beta, unsigned short* __restrict__ C, int M, float invN) {
  const int N = 128, K = 512;
  __shared__ unsigned short As[64 * LDT];
  __shared__ unsigned short Bs[128 * LDT];
  __shared__ float scs[512], shs[512];
  int tid = threadIdx.x;
  int m0 = blockIdx.y * 64;
  int w = tid >> 6, lane = tid & 63;
  int wm = (w >> 1) * 32, wn = (w & 1) * 64;

  // fused BN1 finalize (per-block, redundant but trivial)
  for (int c = tid; c < 512; c += 256) {
    float mean = accum[c] * invN;
    float var = accum[512 + c] * invN - mean * mean;
    float s = gamma[c] * rsqrtf(var + 1e-5f);
    scs[c] = s;
    shs[c] = beta[c] - mean * s;
  }
  __syncthreads();

  f32x4 acc[2][4];
  #pragma unroll
  for (int i = 0; i < 2; i++)
    #pragma unroll
    for (int j = 0; j < 4; j++) acc[i][j] = (f32x4){0.f, 0.f, 0.f, 0.f};

  for (int k0 = 0; k0 < K; k0 += 64) {
    // stage A: BN+ReLU on the fly (64 rows x 8 segs = 512 slots, 2/thread)
    #pragma unroll
    for (int r = 0; r < 2; r++) {
      int idx = r * 256 + tid;        // 0..511
      int row = idx >> 3;             // 0..63
      int seg = (idx & 7) * 8;        // 0..56
      int gr = m0 + row;
      u16x8 v = (u16x8){0, 0, 0, 0, 0, 0, 0, 0};
      if (gr < M) v = *reinterpret_cast<const u16x8*>(&A[(size_t)gr * K + k0 + seg]);
      int c = k0 + seg;
      u16x8 p;
      #pragma unroll
      for (int j = 0; j < 8; j++) {
        float f = fmaxf(bf2f(v[j]) * scs[c + j] + shs[c + j], 0.f);
        p[j] = f2bf(f);
      }
      *reinterpret_cast<u16x8*>(&As[row * LDT + seg]) = p;
    }
    // stage B (128 rows x 8 segs = 1024 slots, 4/thread)
    #pragma unroll
    for (int r = 0; r < 4; r++) {
      int idx = r * 256 + tid;
      int n = idx >> 3;
      int seg = (idx & 7) * 8;
      u16x8 v = *reinterpret_cast<const u16x8*>(&Bt[(size_t)n * K + k0 + seg]);
      *reinterpret_cast<u16x8*>(&Bs[n * LDT + seg]) = v;
    }
    __syncthreads();
    #pragma unroll
    for (int ks = 0; ks < 2; ks++) {
      s16x8 af[2], bfr[4];
      #pragma unroll
      for (int i = 0; i < 2; i++)
        af[i] = *reinterpret_cast<const s16x8*>(
            &As[(wm + i * 16 + (lane & 15)) * LDT + ks * 32 + (lane >> 4) * 8]);
      #pragma unroll
      for (int j = 0; j < 4; j++)
        bfr[j] = *reinterpret_cast<const s16x8*>(
            &Bs[(wn + j * 16 + (lane & 15)) * LDT + ks * 32 + (lane >> 4) * 8]);
      #pragma unroll
      for (int i = 0; i < 2; i++)
        #pragma unroll
        for (int j = 0; j < 4; j++)
          acc[i][j] = __builtin_amdgcn_mfma_f32_16x16x32_bf16(af[i], bfr[j], acc[i][j], 0, 0, 0);
    }
    __syncthreads();
  }
  #pragma unroll
  for (int i = 0; i < 2; i++) {
    #pragma unroll
    for (int j = 0; j < 4; j++) {
      int col = wn + j * 16 + (lane & 15);
      #pragma unroll
      for (int r = 0; r < 4; r++) {
        int row = m0 + wm + i * 16 + (lane >> 4) * 4 + r;
        if (row < M) C[(size_t)row * N + col] = f2bf(acc[i][j][r]);
      }
    }
  }
}

// ---------------- aggregation + fused BN stats (bf16 in / bf16 out, fp32 accum) -------------
// R12 node layout (8 nodes/wave, 1563 blocks — halves the contended-atomic tail vs 4/wave)
// + 8-deep edge unroll (8 independent 1KB-row gathers in flight per lane).
// Stats on the STORED bf16 value (matches the former bn_stats pass semantics).
__global__ void agg512_kernel(const unsigned short* __restrict__ h, const int* __restrict__ offsets,
                              const int* __restrict__ csr, const float* __restrict__ inv_s,
                              unsigned short* __restrict__ out, float* __restrict__ accum, int n) {
  __shared__ float rs[512], rq[512];
  int wv = threadIdx.x >> 6, lane = threadIdx.x & 63;
  for (int c = threadIdx.x; c < 512; c += 256) { rs[c] = 0.f; rq[c] = 0.f; }
  __syncthreads();
  const u16x8* h8 = reinterpret_cast<const u16x8*>(h);  // 64 segs/row
  float s[8], qsum[8];
  #pragma unroll
  for (int j = 0; j < 8; j++) { s[j] = 0.f; qsum[j] = 0.f; }
  for (int i = 0; i < 8; i++) {
    int node = blockIdx.x * 32 + wv * 8 + i;
    if (node >= n) break;
    float di = inv_s[node];
    size_t rb = (size_t)node * 64;
    float acc[8];
    u16x8 v0 = h8[rb + lane];
    float dd = di * di;
    #pragma unroll
    for (int j = 0; j < 8; j++) acc[j] = bf2f(v0[j]) * dd;
    int e = offsets[node], e1 = offsets[node + 1];
    for (; e + 7 < e1; e += 8) {
      int si[8];
      float wi[8];
      u16x8 vi[8];
      #pragma unroll
      for (int k = 0; k < 8; k++) si[k] = csr[e + k];
      #pragma unroll
      for (int k = 0; k < 8; k++) wi[k] = inv_s[si[k]] * di;
      #pragma unroll
      for (int k = 0; k < 8; k++) vi[k] = h8[(size_t)si[k] * 64 + lane];
      #pragma unroll
      for (int j = 0; j < 8; j++) {
        float a = acc[j];
        #pragma unroll
        for (int k = 0; k < 8; k++) a += bf2f(vi[k][j]) * wi[k];
        acc[j] = a;
      }
    }
    for (; e < e1; e++) {
      int sA = csr[e];
      float wA = inv_s[sA] * di;
      u16x8 vA = h8[(size_t)sA * 64 + lane];
      #pragma unroll
      for (int j = 0; j < 8; j++) acc[j] += bf2f(vA[j]) * wA;
    }
    u16x8 o;
    #pragma unroll
    for (int j = 0; j < 8; j++) {
      unsigned short b = f2bf(acc[j]);
      o[j] = b;
      float gv = bf2f(b);  // stats on the STORED bf16 value
      s[j] += gv;
      qsum[j] += gv * gv;
    }
    reinterpret_cast<u16x8*>(out)[rb + lane] = o;
  }
  #pragma unroll
  for (int j = 0; j < 8; j++) {
    atomicAdd(&rs[lane * 8 + j], s[j]);
    atomicAdd(&rq[lane * 8 + j], qsum[j]);
  }
  __syncthreads();
  for (int c = threadIdx.x; c < 512; c += 256) {
    atomicAdd(&accum[c], rs[c]);
    atomicAdd(&accum[512 + c], rq[c]);
  }
}

__global__ void agg128_kernel(const unsigned short* __restrict__ h, const int* __restrict__ offsets,
                              const int* __restrict__ csr, const float* __restrict__ inv_s,
                              unsigned short* __restrict__ out, float* __restrict__ accum, int n) {
  __shared__ float rs[128], rq[128];
  int wv = threadIdx.x >> 6, lane = threadIdx.x & 63;
  if (threadIdx.x < 128) { rs[threadIdx.x] = 0.f; rq[threadIdx.x] = 0.f; }
  __syncthreads();
  const unsigned int* h2 = reinterpret_cast<const unsigned int*>(h);  // 64 uints/row
  float s0 = 0.f, q0 = 0.f, s1 = 0.f, q1 = 0.f;
  for (int i = 0; i < 8; i++) {
    int node = blockIdx.x * 32 + wv * 8 + i;
    if (node >= n) break;
    float di = inv_s[node];
    size_t rb = (size_t)node * 64;
    unsigned int u0 = h2[rb + lane];
    float dd = di * di;
    float alo = __uint_as_float(u0 << 16) * dd;
    float ahi = __uint_as_float(u0 & 0xffff0000u) * dd;
    int e = offsets[node], e1 = offsets[node + 1];
    for (; e + 7 < e1; e += 8) {
      int si[8];
      float wi[8];
      unsigned int ui[8];
      #pragma unroll
      for (int k = 0; k < 8; k++) si[k] = csr[e + k];
      #pragma unroll
      for (int k = 0; k < 8; k++) wi[k] = inv_s[si[k]] * di;
      #pragma unroll
      for (int k = 0; k < 8; k++) ui[k] = h2[(size_t)si[k] * 64 + lane];
      #pragma unroll
      for (int k = 0; k < 8; k++) {
        alo += __uint_as_float(ui[k] << 16) * wi[k];
        ahi += __uint_as_float(ui[k] & 0xffff0000u) * wi[k];
      }
    }
    for (; e < e1; e++) {
      int sA = csr[e];
      float wA = inv_s[sA] * di;
      unsigned int uA = h2[(size_t)sA * 64 + lane];
      alo += __uint_as_float(uA << 16) * wA;
      ahi += __uint_as_float(uA & 0xffff0000u) * wA;
    }
    unsigned short blo = f2bf(alo), bhi = f2bf(ahi);
    unsigned int uo = ((unsigned int)bhi << 16) | (unsigned int)blo;
    reinterpret_cast<unsigned int*>(out)[rb + lane] = uo;
    float glo = bf2f(blo), ghi = bf2f(bhi);
    s0 += glo; q0 += glo * glo; s1 += ghi; q1 += ghi * ghi;
  }
  atomicAdd(&rs[2 * lane], s0);
  atomicAdd(&rq[2 * lane], q0);
  atomicAdd(&rs[2 * lane + 1], s1);
  atomicAdd(&rq[2 * lane + 1], q1);
  __syncthreads();
  if (threadIdx.x < 128) {
    atomicAdd(&accum[threadIdx.x], rs[threadIdx.x]);
    atomicAdd(&accum[128 + threadIdx.x], rq[threadIdx.x]);
  }
}

// ---------------- layer 3: tiny GEMM K=128, N=5 (fp32), BN2 finalize+ReLU fused ----------------
__global__ void gemm3_kernel(const unsigned short* __restrict__ A, const float* __restrict__ W,
                             const float* __restrict__ accum, const float* __restrict__ gamma,
                             const float* __restrict__ beta, float* __restrict__ C, int M,
                             float invN) {
  __shared__ float Ws[128 * 5];
  __shared__ float scs[128], shs[128];
  int tid = threadIdx.x;
  for (int i = tid; i < 128 * 5; i += blockDim.x) Ws[i] = W[i];
  if (tid < 128) {
    float mean = accum[tid] * invN;
    float var = accum[128 + tid] * invN - mean * mean;
    float s = gamma[tid] * rsqrtf(var + 1e-5f);
    scs[tid] = s;
    shs[tid] = beta[tid] - mean * s;
  }
  __syncthreads();
  int row = blockIdx.x * blockDim.x + tid;
  if (row >= M) return;
  float acc[5] = {0.f, 0.f, 0.f, 0.f, 0.f};
  const u16x8* a8 = reinterpret_cast<const u16x8*>(A + (size_t)row * 128);
  for (int k8 = 0; k8 < 16; k8++) {
    u16x8 v = a8[k8];
    int k = k8 * 8;
    #pragma unroll
    for (int j = 0; j < 8; j++) {
      float f = fmaxf(bf2f(v[j]) * scs[k + j] + shs[k + j], 0.f);
      #pragma unroll
      for (int c = 0; c < 5; c++) acc[c] += f * Ws[(k + j) * 5 + c];
    }
  }
  #pragma unroll
  for (int j = 0; j < 5; j++) C[(size_t)row * 5 + j] = acc[j];
}

// ---------------- final aggregation + b3 + log_softmax ----------------
__global__ void agg3_lsm_kernel(const float* __restrict__ h, const int* __restrict__ offsets,
                                const int* __restrict__ csr, const float* __restrict__ inv_s,
                                const float* __restrict__ b3, float* __restrict__ out, int n) {
  int node = blockIdx.x * blockDim.x + threadIdx.x;
  if (node >= n) return;
  float di = inv_s[node];
  float acc[5];
  #pragma unroll
  for (int j = 0; j < 5; j++) acc[j] = h[(size_t)node * 5 + j] * di * di;
  int s0 = offsets[node], s1 = offsets[node + 1];
  for (int e = s0; e < s1; e++) {
    int s = csr[e];
    float wgt = inv_s[s] * di;
    #pragma unroll
    for (int j = 0; j < 5; j++) acc[j] += h[(size_t)s * 5 + j] * wgt;
  }
  #pragma unroll
  for (int j = 0; j < 5; j++) acc[j] += b3[j];
  float m = acc[0];
  #pragma unroll
  for (int j = 1; j < 5; j++) m = fmaxf(m, acc[j]);
  float sum = 0.f;
  #pragma unroll
  for (int j = 0; j < 5; j++) sum += expf(acc[j] - m);
  float lse = logf(sum);
  #pragma unroll
  for (int j = 0; j < 5; j++) out[(size_t)node * 5 + j] = acc[j] - m - lse;
}

// ---------------- launcher ----------------
extern "C" void kernel_launch(void* const* d_in, const int* in_sizes, int n_in,
                              void* d_out, int out_size, void* d_ws, size_t ws_size,
                              hipStream_t stream) {
  const float* x      = (const float*)d_in[0];
  const int*   ei     = (const int*)d_in[1];
  const float* W1     = (const float*)d_in[2];
  const float* b3     = (const float*)d_in[7];
  const float* W2     = (const float*)d_in[4];
  const float* W3     = (const float*)d_in[6];
  const float* gamma1 = (const float*)d_in[8];
  const float* beta1  = (const float*)d_in[9];
  const float* gamma2 = (const float*)d_in[10];
  const float* beta2  = (const float*)d_in[11];

  const int N = in_sizes[0] / 1536;
  const int E = in_sizes[1] / 2;
  const int* src = ei;
  const int* dst = ei + E;

  const int mblocks = (N + 127) / 128;      // 391
  const int Mpad = mblocks * 128;           // 50048
  const int nb = (N + 255) / 256;

  char* ws = (char*)d_ws;
  size_t szRA = alignup((size_t)N * 512 * sizeof(float));
  size_t szXB = alignup((size_t)Mpad * 1536 * sizeof(unsigned short));
  char* RAb = ws;                            // region A (bf16 H1 / bf16 H2 / f32 H3)
  char* RBb = ws + szRA;                     // region B (G1/G2)
  char* sp = ws + szRA + szXB;
  // zero-initialized group (one memset): counts, cursor, accumA, accumB
  char* zbase = sp;
  int* counts    = (int*)sp;          sp += alignup((size_t)N * 4);
  int* cursor    = (int*)sp;          sp += alignup((size_t)N * 4);
  float* accumA  = (float*)sp;        sp += alignup(1024 * 4);
  float* accumB  = (float*)sp;        sp += alignup(256 * 4);
  size_t zspan = (size_t)(sp - zbase);
  int* offsets  = (int*)sp;           sp += alignup((size_t)(N + 1) * 4);
  int* csr_src  = (int*)sp;           sp += alignup((size_t)E * 4);
  float* inv_s  = (float*)sp;         sp += alignup((size_t)N * 4);
  unsigned short* W1t = (unsigned short*)sp; sp += alignup((size_t)512 * 1536 * 2);
  unsigned short* W2t = (unsigned short*)sp; sp += alignup((size_t)128 * 512 * 2);
  int* bsum     = (int*)sp;           sp += alignup(256 * 4);

  unsigned short* H1  = (unsigned short*)RAb;  // N x 512 bf16
  unsigned short* G1  = (unsigned short*)RBb;  // N x 512 bf16 (post-agg)
  unsigned short* H2  = (unsigned short*)RAb;  // N x 128 bf16
  unsigned short* G2  = (unsigned short*)RBb;  // N x 128 bf16
  float*          H3  = (float*)RAb;           // N x 5 f32

  // ---- single memset for all zero-init scratch ----
  hipMemsetAsync(zbase, 0, zspan, stream);

  // ---- graph preprocessing ----
  count_kernel<<<(E + 255) / 256, 256, 0, stream>>>(dst, counts, E);
  block_sum_kernel<<<nb, 256, 0, stream>>>(counts, bsum, N);
  scan_bsum_kernel<<<1, 256, 0, stream>>>(bsum, nb);
  scan_apply_kernel<<<nb, 256, 0, stream>>>(counts, bsum, offsets, inv_s, N);
  fill_kernel<<<(E + 255) / 256, 256, 0, stream>>>(src, dst, offsets, cursor, csr_src, E);

  // ---- weights (both transposes, one launch) ----
  transpose_both_kernel<<<832, 256, 0, stream>>>(W1, W1t, W2, W2t);

  int aggblocks32 = (N + 31) / 32;
  float invN = 1.0f / N;

  // ---- layer 1 (f32 x staged directly; cvt fused into fragment path) ----
  gemm1_kernel<<<dim3(2, mblocks), 512, 0, stream>>>(x, W1t, H1, N);
  agg512_kernel<<<aggblocks32, 256, 0, stream>>>(H1, offsets, csr_src, inv_s, G1, accumA, N);

  // ---- layer 2 (BN1 finalize + ReLU fused into A staging; BM=64 balanced grid) ----
  gemm2_kernel<<<dim3(1, (N + 63) / 64), 256, 0, stream>>>(G1, W2t, accumA, gamma1, beta1, H2, N,
                                                           invN);
  agg128_kernel<<<aggblocks32, 256, 0, stream>>>(H2, offsets, csr_src, inv_s, G2, accumB, N);

  // ---- layer 3 (BN2 finalize + ReLU fused) ----
  gemm3_kernel<<<(N + 255) / 256, 256, 0, stream>>>(G2, W3, accumB, gamma2, beta2, H3, N, invN);
  agg3_lsm_kernel<<<(N + 255) / 256, 256, 0, stream>>>(H3, offsets, csr_src, inv_s, b3,
                                                       (float*)d_out, N);
}

// Round 15
// 555.270 us; speedup vs baseline: 1.1522x; 1.0064x over previous
//
#include <hip/hip_runtime.h>
#include <cstddef>
#include <cstdint>

// ---------------- types / helpers ----------------
typedef short s16x8 __attribute__((ext_vector_type(8)));
typedef unsigned short u16x4 __attribute__((ext_vector_type(4)));
typedef unsigned short u16x8 __attribute__((ext_vector_type(8)));
typedef float f32x4 __attribute__((ext_vector_type(4)));

__device__ __forceinline__ unsigned short f2bf(float f) {
  unsigned int u = __float_as_uint(f);
  u = (u + 0x7fffu + ((u >> 16) & 1u)) >> 16;
  return (unsigned short)u;
}
__device__ __forceinline__ float bf2f(unsigned short u) {
  return __uint_as_float(((unsigned int)u) << 16);
}

__device__ __forceinline__ void gl2lds16(const unsigned short* g, unsigned short* l) {
  __builtin_amdgcn_global_load_lds(
      (const __attribute__((address_space(1))) unsigned int*)g,
      (__attribute__((address_space(3))) unsigned int*)l, 16, 0, 0);
}
__device__ __forceinline__ void gl2lds16f(const float* g, float* l) {
  __builtin_amdgcn_global_load_lds(
      (const __attribute__((address_space(1))) unsigned int*)g,
      (__attribute__((address_space(3))) unsigned int*)l, 16, 0, 0);
}

static inline size_t alignup(size_t x) { return (x + 255) & ~(size_t)255; }

// ---------------- graph preprocessing ----------------
__global__ void count_kernel(const int* __restrict__ dst, int* __restrict__ counts, int E) {
  int e = blockIdx.x * blockDim.x + threadIdx.x;
  if (e < E) atomicAdd(&counts[dst[e]], 1);
}

__global__ void block_sum_kernel(const int* __restrict__ counts, int* __restrict__ bsum, int n) {
  __shared__ int red[256];
  int i = blockIdx.x * 256 + threadIdx.x;
  red[threadIdx.x] = (i < n) ? counts[i] : 0;
  __syncthreads();
  #pragma unroll
  for (int o = 128; o > 0; o >>= 1) {
    if (threadIdx.x < o) red[threadIdx.x] += red[threadIdx.x + o];
    __syncthreads();
  }
  if (threadIdx.x == 0) bsum[blockIdx.x] = red[0];
}

__global__ void scan_bsum_kernel(int* __restrict__ bsum, int nb) {
  __shared__ int s[256];
  int t = threadIdx.x;
  s[t] = (t < nb) ? bsum[t] : 0;
  __syncthreads();
  #pragma unroll
  for (int o = 1; o < 256; o <<= 1) {
    int v = (t >= o) ? s[t - o] : 0;
    __syncthreads();
    s[t] += v;
    __syncthreads();
  }
  if (t < nb) bsum[t] = (t == 0) ? 0 : s[t - 1];  // exclusive
}

// scan_apply + fused invsqrt (counts already in registers)
__global__ void scan_apply_kernel(const int* __restrict__ counts, const int* __restrict__ bpre,
                                  int* __restrict__ offsets, float* __restrict__ inv_s, int n) {
  __shared__ int s[256];
  int t = threadIdx.x;
  int i = blockIdx.x * 256 + t;
  int c = (i < n) ? counts[i] : 0;
  s[t] = c;
  __syncthreads();
  #pragma unroll
  for (int o = 1; o < 256; o <<= 1) {
    int v = (t >= o) ? s[t - o] : 0;
    __syncthreads();
    s[t] += v;
    __syncthreads();
  }
  if (i < n) {
    offsets[i + 1] = s[t] + bpre[blockIdx.x];
    inv_s[i] = rsqrtf((float)(c + 1));  // +1 self loop
  }
  if (i == 0) offsets[0] = 0;
}

__global__ void fill_kernel(const int* __restrict__ src, const int* __restrict__ dst,
                            const int* __restrict__ offsets, int* __restrict__ cursor,
                            int* __restrict__ csr_src, int E) {
  int e = blockIdx.x * blockDim.x + threadIdx.x;
  if (e >= E) return;
  int d = dst[e];
  int pos = atomicAdd(&cursor[d], 1);
  csr_src[offsets[d] + pos] = src[e];
}

// ---------------- both weight transposes in one launch ----------------
// W[K][N] f32 -> Wt[N][K] bf16.  blocks 0..767: W1 (48x16), 768..831: W2 (16x4).
__global__ void transpose_both_kernel(const float* __restrict__ W1, unsigned short* __restrict__ W1t,
                                      const float* __restrict__ W2, unsigned short* __restrict__ W2t) {
  __shared__ float tile[32][33];
  int b = blockIdx.x;
  const float* W;
  unsigned short* Wt;
  int K, N, kx, ny;
  if (b < 768) { W = W1; Wt = W1t; K = 1536; N = 512; kx = b % 48; ny = b / 48; }
  else { b -= 768; W = W2; Wt = W2t; K = 512; N = 128; kx = b % 16; ny = b / 16; }
  int k0 = kx * 32, n0 = ny * 32;
  int tx = threadIdx.x & 31, ty = threadIdx.x >> 5;
  #pragma unroll
  for (int i = 0; i < 32; i += 8)
    tile[ty + i][tx] = W[(size_t)(k0 + ty + i) * N + n0 + tx];
  __syncthreads();
  #pragma unroll
  for (int i = 0; i < 32; i += 8)
    Wt[(size_t)(n0 + ty + i) * K + k0 + tx] = f2bf(tile[tx][ty + i]);
}

// ---------------- GEMM1: f32 A[M][1536] x Bt[512][1536] bf16 -> C[M][512] bf16 --------------
// R10 form — FROZEN. 2 buffers, 1 __syncthreads/tile, all global_load_lds, cvt_pk in
// fragment path, 8 waves (2x4) of 64x64, 64KB LDS (2 blk/CU, the measured optimum).
// A: 128B rows, 8 slots, slot^(row&7) (bank-free). B: 64B rows, slot^((row>>1)&3) (bank-free).
__global__ __launch_bounds__(512) void gemm1_kernel(
    const float* __restrict__ A, const unsigned short* __restrict__ B,
    unsigned short* __restrict__ C, int M) {
  __shared__ __align__(16) float As[2][128 * 32];
  __shared__ __align__(16) unsigned short Bs[2][256 * 32];
  const int K = 1536;
  const int NT = 48;  // K / 32
  int tid = threadIdx.x, lane = tid & 63, w = tid >> 6;

  // bijective XCD swizzle (m204)
  int nwg = gridDim.x * gridDim.y;  // 782
  int orig = blockIdx.y * gridDim.x + blockIdx.x;
  int q = nwg >> 3, r = nwg & 7;
  int xcd = orig & 7, loc = orig >> 3;
  int wg = (xcd < r) ? xcd * (q + 1) + loc : r * (q + 1) + (xcd - r) * q + loc;
  int bx = wg & 1, by = wg >> 1;  // gridDim.x == 2

  int m0 = by * 128, n0 = bx * 256;
  int wm = (w >> 2) * 64, wn = (w & 3) * 64;

  f32x4 acc[4][4];
  #pragma unroll
  for (int i = 0; i < 4; i++)
    #pragma unroll
    for (int j = 0; j < 4; j++) acc[i][j] = (f32x4){0.f, 0.f, 0.f, 0.f};

  // A staging (f32): 128x32 = 16KB = 2 passes x (512 thr x 16B). row=idx>>3, slot=idx&7.
  int row0 = tid >> 3, slot0 = tid & 7;
  int row1 = 64 + row0;
  const float* agp0 = &A[(size_t)min(m0 + row0, M - 1) * K + ((slot0 ^ (row0 & 7)) << 2)];
  const float* agp1 = &A[(size_t)min(m0 + row1, M - 1) * K + ((slot0 ^ (row1 & 7)) << 2)];
  int adst0 = tid * 4, adst1 = (512 + tid) * 4;  // f32 elems, linear
  // B staging (bf16): 256x32 = 16KB = 2 passes. row = tid>>2, 4 slots of 8 bf16.
  int brow = tid >> 2, bslot = tid & 3;
  int bsrc = (bslot ^ ((brow >> 1) & 3)) << 3;
  const unsigned short* bgp0 = &B[(size_t)(n0 + brow) * K + bsrc];
  const unsigned short* bgp1 = &B[(size_t)(n0 + 128 + brow) * K + bsrc];
  int bdst0 = tid * 8, bdst1 = (512 + tid) * 8;

  // prologue: stage tile 0 into buf 0
  gl2lds16f(agp0, &As[0][adst0]);
  gl2lds16f(agp1, &As[0][adst1]);
  gl2lds16(bgp0, &Bs[0][bdst0]);
  gl2lds16(bgp1, &Bs[0][bdst1]);
  __syncthreads();

  int cur = 0;
  for (int t = 0; t < NT; t++) {
    if (t + 1 < NT) {
      int kb = (t + 1) * 32;
      gl2lds16f(agp0 + kb, &As[cur ^ 1][adst0]);
      gl2lds16f(agp1 + kb, &As[cur ^ 1][adst1]);
      gl2lds16(bgp0 + kb, &Bs[cur ^ 1][bdst0]);
      gl2lds16(bgp1 + kb, &Bs[cur ^ 1][bdst1]);
    }
    // fragments from buf[cur]; A converted f32->bf16 here
    int jc = lane >> 4;  // 0..3
    s16x8 af[4], bfr[4];
    #pragma unroll
    for (int i = 0; i < 4; i++) {
      int rr = wm + i * 16 + (lane & 15);
      f32x4 v0 = *reinterpret_cast<const f32x4*>(&As[cur][rr * 32 + (((2 * jc) ^ (rr & 7)) << 2)]);
      f32x4 v1 = *reinterpret_cast<const f32x4*>(&As[cur][rr * 32 + (((2 * jc + 1) ^ (rr & 7)) << 2)]);
      unsigned int c0, c1, c2, c3;
      asm("v_cvt_pk_bf16_f32 %0, %1, %2" : "=v"(c0) : "v"(v0[0]), "v"(v0[1]));
      asm("v_cvt_pk_bf16_f32 %0, %1, %2" : "=v"(c1) : "v"(v0[2]), "v"(v0[3]));
      asm("v_cvt_pk_bf16_f32 %0, %1, %2" : "=v"(c2) : "v"(v1[0]), "v"(v1[1]));
      asm("v_cvt_pk_bf16_f32 %0, %1, %2" : "=v"(c3) : "v"(v1[2]), "v"(v1[3]));
      uint4 pk;
      pk.x = c0; pk.y = c1; pk.z = c2; pk.w = c3;
      af[i] = __builtin_bit_cast(s16x8, pk);
      int rn = wn + i * 16 + (lane & 15);
      bfr[i] = *reinterpret_cast<const s16x8*>(
          &Bs[cur][rn * 32 + ((jc ^ ((rn >> 1) & 3)) << 3)]);
    }
    #pragma unroll
    for (int i = 0; i < 4; i++)
      #pragma unroll
      for (int j = 0; j < 4; j++)
        acc[i][j] = __builtin_amdgcn_mfma_f32_16x16x32_bf16(af[i], bfr[j], acc[i][j], 0, 0, 0);
    __syncthreads();  // drains next-tile DMA (flew under MFMA) + frees buf[cur]
    cur ^= 1;
  }

  #pragma unroll
  for (int i = 0; i < 4; i++) {
    #pragma unroll
    for (int j = 0; j < 4; j++) {
      int col = n0 + wn + j * 16 + (lane & 15);
      #pragma unroll
      for (int r2 = 0; r2 < 4; r2++) {
        int row = m0 + wm + i * 16 + (lane >> 4) * 4 + r2;
        if (row < M) C[(size_t)row * 512 + col] = f2bf(acc[i][j][r2]);
      }
    }
  }
}

// ---------------- GEMM2: bf16 A (BN1+ReLU fused) x W2t bf16 -> C bf16 ----------------
// gemm1-recipe pipeline: double-buffered, B via global_load_lds (pre-swizzled source),
// A reg-staged with issue-early/write-late (R2 schedule), ONE barrier per K-tile.
// Both tiles: 128B rows, 8 slots of 16B, involution slot^(row&7) (gemm1-A bank-free form).
// LDS = 2x(8KB A + 16KB B) + 4KB scs/shs = 52KB -> 3 blk/CU.
__global__ __launch_bounds__(256) void gemm2_kernel(
    const unsigned short* __restrict__ A, const unsigned short* __restrict__ Bt,
    const float* __restrict__ accum, const float* __restrict__ gamma,
    const float* __restrict__ beta, unsigned short* __restrict__ C, int M, float invN) {
  const int K = 512;
  const int NT = 8;  // K / 64
  __shared__ __align__(16) unsigned short As[2][64 * 64];
  __shared__ __align__(16) unsigned short Bs[2][128 * 64];
  __shared__ float scs[512], shs[512];
  int tid = threadIdx.x;
  int m0 = blockIdx.x * 64;
  int w = tid >> 6, lane = tid & 63;
  int wm = (w >> 1) * 32, wn = (w & 1) * 64;

  // fused BN1 finalize (per-block, redundant but trivial)
  for (int c = tid; c < 512; c += 256) {
    float mean = accum[c] * invN;
    float var = accum[512 + c] * invN - mean * mean;
    float s = gamma[c] * rsqrtf(var + 1e-5f);
    scs[c] = s;
    shs[c] = beta[c] - mean * s;
  }
  __syncthreads();  // scs/shs ready before first A transform

  f32x4 acc[2][4];
  #pragma unroll
  for (int i = 0; i < 2; i++)
    #pragma unroll
    for (int j = 0; j < 4; j++) acc[i][j] = (f32x4){0.f, 0.f, 0.f, 0.f};

  // A staging (reg path): 64x64 tile = 512 u16x8 slots, 2/thread.
  // pass r: idx = r*256+tid; row = idx>>3, slot = idx&7. Linear source, dest-side swizzle.
  int arow = tid >> 3, aslot = tid & 7;     // pass 0 row; pass 1 row = arow+32
  int ac0 = aslot * 8;                      // channel base within the k-tile
  int adst0 = arow * 64 + ((aslot ^ (arow & 7)) << 3);
  int adst1 = (arow + 32) * 64 + ((aslot ^ ((arow + 32) & 7)) << 3);
  bool aok0 = (m0 + arow) < M, aok1 = (m0 + arow + 32) < M;
  const unsigned short* agp0 = &A[(size_t)(m0 + arow) * K + ac0];
  const unsigned short* agp1 = &A[(size_t)(m0 + arow + 32) * K + ac0];
  // B staging (gl2lds): 128x64 tile = 1024 entries of 16B, 4/thread; pre-swizzled source.
  const unsigned short* bgp[4];
  int bdst[4];
  #pragma unroll
  for (int p = 0; p < 4; p++) {
    int idx = p * 256 + tid;
    int row = idx >> 3, slot = idx & 7;
    bgp[p] = &Bt[(size_t)row * K + ((slot ^ (row & 7)) << 3)];
    bdst[p] = idx * 8;  // linear dest (elems)
  }

  auto bn_write = [&](unsigned short* AsW, int kb, u16x8 v0, u16x8 v1) {
    u16x8 p0, p1;
    int c0 = kb + ac0;
    #pragma unroll
    for (int j = 0; j < 8; j++) {
      p0[j] = f2bf(fmaxf(bf2f(v0[j]) * scs[c0 + j] + shs[c0 + j], 0.f));
      p1[j] = f2bf(fmaxf(bf2f(v1[j]) * scs[c0 + j] + shs[c0 + j], 0.f));
    }
    *reinterpret_cast<u16x8*>(&AsW[adst0]) = p0;
    *reinterpret_cast<u16x8*>(&AsW[adst1]) = p1;
  };
  auto load_a = [&](int kb, u16x8& v0, u16x8& v1) {
    v0 = (u16x8){0, 0, 0, 0, 0, 0, 0, 0};
    v1 = (u16x8){0, 0, 0, 0, 0, 0, 0, 0};
    if (aok0) v0 = *reinterpret_cast<const u16x8*>(agp0 + kb);
    if (aok1) v1 = *reinterpret_cast<const u16x8*>(agp1 + kb);
  };

  // prologue: B(0) dma; A(0) load+transform+write
  #pragma unroll
  for (int p = 0; p < 4; p++) gl2lds16(bgp[p], &Bs[0][bdst[p]]);
  {
    u16x8 v0, v1;
    load_a(0, v0, v1);
    bn_write(As[0], 0, v0, v1);
  }
  __syncthreads();

  int cur = 0;
  for (int t = 0; t < NT; t++) {
    u16x8 n0r, n1r;
    if (t + 1 < NT) {
      int kb = (t + 1) * 64;
      #pragma unroll
      for (int p = 0; p < 4; p++) gl2lds16(bgp[p] + kb, &Bs[cur ^ 1][bdst[p]]);
      load_a(kb, n0r, n1r);  // issue early: lands during MFMA phase
    }
    #pragma unroll
    for (int ks = 0; ks < 2; ks++) {
      int s = ks * 4 + (lane >> 4);
      s16x8 af[2], bfr[4];
      #pragma unroll
      for (int i = 0; i < 2; i++) {
        int ra = wm + i * 16 + (lane & 15);
        af[i] = *reinterpret_cast<const s16x8*>(&As[cur][ra * 64 + ((s ^ (ra & 7)) << 3)]);
      }
      #pragma unroll
      for (int j = 0; j < 4; j++) {
        int rb = wn + j * 16 + (lane & 15);
        bfr[j] = *reinterpret_cast<const s16x8*>(&Bs[cur][rb * 64 + ((s ^ (rb & 7)) << 3)]);
      }
      #pragma unroll
      for (int i = 0; i < 2; i++)
        #pragma unroll
        for (int j = 0; j < 4; j++)
          acc[i][j] = __builtin_amdgcn_mfma_f32_16x16x32_bf16(af[i], bfr[j], acc[i][j], 0, 0, 0);
    }
    if (t + 1 < NT) bn_write(As[cur ^ 1], (t + 1) * 64, n0r, n1r);  // write-late
    __syncthreads();
    cur ^= 1;
  }

  #pragma unroll
  for (int i = 0; i < 2; i++) {
    #pragma unroll
    for (int j = 0; j < 4; j++) {
      int col = wn + j * 16 + (lane & 15);
      #pragma unroll
      for (int r = 0; r < 4; r++) {
        int row = m0 + wm + i * 16 + (lane >> 4) * 4 + r;
        if (row < M) C[(size_t)row * 128 + col] = f2bf(acc[i][j][r]);
      }
    }
  }
}

// ---------------- aggregation + fused BN stats (bf16 in / bf16 out, fp32 accum) -------------
// 8 nodes/wave (1563 blocks) + 8-deep edge unroll (R14 form — measured best).
// Stats on the STORED bf16 value (matches the former bn_stats pass semantics).
__global__ void agg512_kernel(const unsigned short* __restrict__ h, const int* __restrict__ offsets,
                              const int* __restrict__ csr, const float* __restrict__ inv_s,
                              unsigned short* __restrict__ out, float* __restrict__ accum, int n) {
  __shared__ float rs[512], rq[512];
  int wv = threadIdx.x >> 6, lane = threadIdx.x & 63;
  for (int c = threadIdx.x; c < 512; c += 256) { rs[c] = 0.f; rq[c] = 0.f; }
  __syncthreads();
  const u16x8* h8 = reinterpret_cast<const u16x8*>(h);  // 64 segs/row
  float s[8], qsum[8];
  #pragma unroll
  for (int j = 0; j < 8; j++) { s[j] = 0.f; qsum[j] = 0.f; }
  for (int i = 0; i < 8; i++) {
    int node = blockIdx.x * 32 + wv * 8 + i;
    if (node >= n) break;
    float di = inv_s[node];
    size_t rb = (size_t)node * 64;
    float acc[8];
    u16x8 v0 = h8[rb + lane];
    float dd = di * di;
    #pragma unroll
    for (int j = 0; j < 8; j++) acc[j] = bf2f(v0[j]) * dd;
    int e = offsets[node], e1 = offsets[node + 1];
    for (; e + 7 < e1; e += 8) {
      int si[8];
      float wi[8];
      u16x8 vi[8];
      #pragma unroll
      for (int k = 0; k < 8; k++) si[k] = csr[e + k];
      #pragma unroll
      for (int k = 0; k < 8; k++) wi[k] = inv_s[si[k]] * di;
      #pragma unroll
      for (int k = 0; k < 8; k++) vi[k] = h8[(size_t)si[k] * 64 + lane];
      #pragma unroll
      for (int j = 0; j < 8; j++) {
        float a = acc[j];
        #pragma unroll
        for (int k = 0; k < 8; k++) a += bf2f(vi[k][j]) * wi[k];
        acc[j] = a;
      }
    }
    for (; e < e1; e++) {
      int sA = csr[e];
      float wA = inv_s[sA] * di;
      u16x8 vA = h8[(size_t)sA * 64 + lane];
      #pragma unroll
      for (int j = 0; j < 8; j++) acc[j] += bf2f(vA[j]) * wA;
    }
    u16x8 o;
    #pragma unroll
    for (int j = 0; j < 8; j++) {
      unsigned short b = f2bf(acc[j]);
      o[j] = b;
      float gv = bf2f(b);  // stats on the STORED bf16 value
      s[j] += gv;
      qsum[j] += gv * gv;
    }
    reinterpret_cast<u16x8*>(out)[rb + lane] = o;
  }
  #pragma unroll
  for (int j = 0; j < 8; j++) {
    atomicAdd(&rs[lane * 8 + j], s[j]);
    atomicAdd(&rq[lane * 8 + j], qsum[j]);
  }
  __syncthreads();
  for (int c = threadIdx.x; c < 512; c += 256) {
    atomicAdd(&accum[c], rs[c]);
    atomicAdd(&accum[512 + c], rq[c]);
  }
}

__global__ void agg128_kernel(const unsigned short* __restrict__ h, const int* __restrict__ offsets,
                              const int* __restrict__ csr, const float* __restrict__ inv_s,
                              unsigned short* __restrict__ out, float* __restrict__ accum, int n) {
  __shared__ float rs[128], rq[128];
  int wv = threadIdx.x >> 6, lane = threadIdx.x & 63;
  if (threadIdx.x < 128) { rs[threadIdx.x] = 0.f; rq[threadIdx.x] = 0.f; }
  __syncthreads();
  const unsigned int* h2 = reinterpret_cast<const unsigned int*>(h);  // 64 uints/row
  float s0 = 0.f, q0 = 0.f, s1 = 0.f, q1 = 0.f;
  for (int i = 0; i < 8; i++) {
    int node = blockIdx.x * 32 + wv * 8 + i;
    if (node >= n) break;
    float di = inv_s[node];
    size_t rb = (size_t)node * 64;
    unsigned int u0 = h2[rb + lane];
    float dd = di * di;
    float alo = __uint_as_float(u0 << 16) * dd;
    float ahi = __uint_as_float(u0 & 0xffff0000u) * dd;
    int e = offsets[node], e1 = offsets[node + 1];
    for (; e + 7 < e1; e += 8) {
      int si[8];
      float wi[8];
      unsigned int ui[8];
      #pragma unroll
      for (int k = 0; k < 8; k++) si[k] = csr[e + k];
      #pragma unroll
      for (int k = 0; k < 8; k++) wi[k] = inv_s[si[k]] * di;
      #pragma unroll
      for (int k = 0; k < 8; k++) ui[k] = h2[(size_t)si[k] * 64 + lane];
      #pragma unroll
      for (int k = 0; k < 8; k++) {
        alo += __uint_as_float(ui[k] << 16) * wi[k];
        ahi += __uint_as_float(ui[k] & 0xffff0000u) * wi[k];
      }
    }
    for (; e < e1; e++) {
      int sA = csr[e];
      float wA = inv_s[sA] * di;
      unsigned int uA = h2[(size_t)sA * 64 + lane];
      alo += __uint_as_float(uA << 16) * wA;
      ahi += __uint_as_float(uA & 0xffff0000u) * wA;
    }
    unsigned short blo = f2bf(alo), bhi = f2bf(ahi);
    unsigned int uo = ((unsigned int)bhi << 16) | (unsigned int)blo;
    reinterpret_cast<unsigned int*>(out)[rb + lane] = uo;
    float glo = bf2f(blo), ghi = bf2f(bhi);
    s0 += glo; q0 += glo * glo; s1 += ghi; q1 += ghi * ghi;
  }
  atomicAdd(&rs[2 * lane], s0);
  atomicAdd(&rq[2 * lane], q0);
  atomicAdd(&rs[2 * lane + 1], s1);
  atomicAdd(&rq[2 * lane + 1], q1);
  __syncthreads();
  if (threadIdx.x < 128) {
    atomicAdd(&accum[threadIdx.x], rs[threadIdx.x]);
    atomicAdd(&accum[128 + threadIdx.x], rq[threadIdx.x]);
  }
}

// ---------------- layer 3: tiny GEMM K=128, N=5 (fp32), BN2 finalize+ReLU fused ----------------
__global__ void gemm3_kernel(const unsigned short* __restrict__ A, const float* __restrict__ W,
                             const float* __restrict__ accum, const float* __restrict__ gamma,
                             const float* __restrict__ beta, float* __restrict__ C, int M,
                             float invN) {
  __shared__ float Ws[128 * 5];
  __shared__ float scs[128], shs[128];
  int tid = threadIdx.x;
  for (int i = tid; i < 128 * 5; i += blockDim.x) Ws[i] = W[i];
  if (tid < 128) {
    float mean = accum[tid] * invN;
    float var = accum[128 + tid] * invN - mean * mean;
    float s = gamma[tid] * rsqrtf(var + 1e-5f);
    scs[tid] = s;
    shs[tid] = beta[tid] - mean * s;
  }
  __syncthreads();
  int row = blockIdx.x * blockDim.x + tid;
  if (row >= M) return;
  float acc[5] = {0.f, 0.f, 0.f, 0.f, 0.f};
  const u16x8* a8 = reinterpret_cast<const u16x8*>(A + (size_t)row * 128);
  for (int k8 = 0; k8 < 16; k8++) {
    u16x8 v = a8[k8];
    int k = k8 * 8;
    #pragma unroll
    for (int j = 0; j < 8; j++) {
      float f = fmaxf(bf2f(v[j]) * scs[k + j] + shs[k + j], 0.f);
      #pragma unroll
      for (int c = 0; c < 5; c++) acc[c] += f * Ws[(k + j) * 5 + c];
    }
  }
  #pragma unroll
  for (int j = 0; j < 5; j++) C[(size_t)row * 5 + j] = acc[j];
}

// ---------------- final aggregation + b3 + log_softmax ----------------
__global__ void agg3_lsm_kernel(const float* __restrict__ h, const int* __restrict__ offsets,
                                const int* __restrict__ csr, const float* __restrict__ inv_s,
                                const float* __restrict__ b3, float* __restrict__ out, int n) {
  int node = blockIdx.x * blockDim.x + threadIdx.x;
  if (node >= n) return;
  float di = inv_s[node];
  float acc[5];
  #pragma unroll
  for (int j = 0; j < 5; j++) acc[j] = h[(size_t)node * 5 + j] * di * di;
  int s0 = offsets[node], s1 = offsets[node + 1];
  for (int e = s0; e < s1; e++) {
    int s = csr[e];
    float wgt = inv_s[s] * di;
    #pragma unroll
    for (int j = 0; j < 5; j++) acc[j] += h[(size_t)s * 5 + j] * wgt;
  }
  #pragma unroll
  for (int j = 0; j < 5; j++) acc[j] += b3[j];
  float m = acc[0];
  #pragma unroll
  for (int j = 1; j < 5; j++) m = fmaxf(m, acc[j]);
  float sum = 0.f;
  #pragma unroll
  for (int j = 0; j < 5; j++) sum += expf(acc[j] - m);
  float lse = logf(sum);
  #pragma unroll
  for (int j = 0; j < 5; j++) out[(size_t)node * 5 + j] = acc[j] - m - lse;
}

// ---------------- launcher ----------------
extern "C" void kernel_launch(void* const* d_in, const int* in_sizes, int n_in,
                              void* d_out, int out_size, void* d_ws, size_t ws_size,
                              hipStream_t stream) {
  const float* x      = (const float*)d_in[0];
  const int*   ei     = (const int*)d_in[1];
  const float* W1     = (const float*)d_in[2];
  const float* b3     = (const float*)d_in[7];
  const float* W2     = (const float*)d_in[4];
  const float* W3     = (const float*)d_in[6];
  const float* gamma1 = (const float*)d_in[8];
  const float* beta1  = (const float*)d_in[9];
  const float* gamma2 = (const float*)d_in[10];
  const float* beta2  = (const float*)d_in[11];

  const int N = in_sizes[0] / 1536;
  const int E = in_sizes[1] / 2;
  const int* src = ei;
  const int* dst = ei + E;

  const int mblocks = (N + 127) / 128;      // 391
  const int Mpad = mblocks * 128;           // 50048
  const int nb = (N + 255) / 256;

  char* ws = (char*)d_ws;
  size_t szRA = alignup((size_t)N * 512 * sizeof(float));
  size_t szXB = alignup((size_t)Mpad * 1536 * sizeof(unsigned short));
  char* RAb = ws;                            // region A (bf16 H1 / bf16 H2 / f32 H3)
  char* RBb = ws + szRA;                     // region B (G1/G2)
  char* sp = ws + szRA + szXB;
  // zero-initialized group (one memset): counts, cursor, accumA, accumB
  char* zbase = sp;
  int* counts    = (int*)sp;          sp += alignup((size_t)N * 4);
  int* cursor    = (int*)sp;          sp += alignup((size_t)N * 4);
  float* accumA  = (float*)sp;        sp += alignup(1024 * 4);
  float* accumB  = (float*)sp;        sp += alignup(256 * 4);
  size_t zspan = (size_t)(sp - zbase);
  int* offsets  = (int*)sp;           sp += alignup((size_t)(N + 1) * 4);
  int* csr_src  = (int*)sp;           sp += alignup((size_t)E * 4);
  float* inv_s  = (float*)sp;         sp += alignup((size_t)N * 4);
  unsigned short* W1t = (unsigned short*)sp; sp += alignup((size_t)512 * 1536 * 2);
  unsigned short* W2t = (unsigned short*)sp; sp += alignup((size_t)128 * 512 * 2);
  int* bsum     = (int*)sp;           sp += alignup(256 * 4);

  unsigned short* H1  = (unsigned short*)RAb;  // N x 512 bf16
  unsigned short* G1  = (unsigned short*)RBb;  // N x 512 bf16 (post-agg)
  unsigned short* H2  = (unsigned short*)RAb;  // N x 128 bf16
  unsigned short* G2  = (unsigned short*)RBb;  // N x 128 bf16
  float*          H3  = (float*)RAb;           // N x 5 f32

  // ---- single memset for all zero-init scratch ----
  hipMemsetAsync(zbase, 0, zspan, stream);

  // ---- graph preprocessing ----
  count_kernel<<<(E + 255) / 256, 256, 0, stream>>>(dst, counts, E);
  block_sum_kernel<<<nb, 256, 0, stream>>>(counts, bsum, N);
  scan_bsum_kernel<<<1, 256, 0, stream>>>(bsum, nb);
  scan_apply_kernel<<<nb, 256, 0, stream>>>(counts, bsum, offsets, inv_s, N);
  fill_kernel<<<(E + 255) / 256, 256, 0, stream>>>(src, dst, offsets, cursor, csr_src, E);

  // ---- weights (both transposes, one launch) ----
  transpose_both_kernel<<<832, 256, 0, stream>>>(W1, W1t, W2, W2t);

  int aggblocks32 = (N + 31) / 32;
  float invN = 1.0f / N;

  // ---- layer 1 (f32 x staged directly; cvt fused into fragment path) ----
  gemm1_kernel<<<dim3(2, mblocks), 512, 0, stream>>>(x, W1t, H1, N);
  agg512_kernel<<<aggblocks32, 256, 0, stream>>>(H1, offsets, csr_src, inv_s, G1, accumA, N);

  // ---- layer 2 (BN1 finalize + ReLU fused into pipelined A staging) ----
  gemm2_kernel<<<(N + 63) / 64, 256, 0, stream>>>(G1, W2t, accumA, gamma1, beta1, H2, N, invN);
  agg128_kernel<<<aggblocks32, 256, 0, stream>>>(H2, offsets, csr_src, inv_s, G2, accumB, N);

  // ---- layer 3 (BN2 finalize + ReLU fused) ----
  gemm3_kernel<<<(N + 255) / 256, 256, 0, stream>>>(G2, W3, accumB, gamma2, beta2, H3, N, invN);
  agg3_lsm_kernel<<<(N + 255) / 256, 256, 0, stream>>>(H3, offsets, csr_src, inv_s, b3,
                                                       (float*)d_out, N);
}